// Round 9
// baseline (44.355 us; speedup 1.0000x reference)
//
#include <hip/hip_runtime.h>
#include <math.h>
#include <type_traits>

#define QDEPTH 10
#define WIRES 10
#define NSTATE 1024
#define NGATES (QDEPTH * WIRES)

typedef float f2 __attribute__((ext_vector_type(2)));

// ---------------------------------------------------------------------------
// Layout: 512 blocks x 256 thr (4 waves = 2 elements, 2 waves/element).
// Stored index s = w<<9 | j<<6 | lane  (w: wave bit9, j: reg bits 8..6,
// lane: bits 5..0). Wire q <-> bit (9-q):
//   bit 9 (wire 0) + bit 2 (wire 7): folded into per-layer CNOT gather
//   bits 8,7,6 (wires 1-3): register gates (pure pk-FMA)
//   bit 5 (wire 4): permlane32_swap   bit 4 (wire 5): permlane16_swap
//   bit 3 (wire 6): DPP row_ror:8     bits 1,0 (wires 8,9): DPP quad_perm
// LDS store address A(p) = ((p>>3)<<3)|((p&3)<<1)|bit2(p): {p,p^4} adjacent.
// Fold table entry = A(G_l(s)) (self address); partner ^1, wave-partner ^512;
// gate-row signs from bits 0 (=h2) and 9 (=h9) of the entry. 1 barrier/layer.
// ---------------------------------------------------------------------------
constexpr unsigned sigma_apply(int q, int r, unsigned i) {
    int cb = 9 - q, tb = 9 - ((q + r) % 10);
    return i ^ (((i >> cb) & 1u) << tb);
}
constexpr unsigned G_apply(int l, unsigned i) {
    int r = (l % 9) + 1;
    for (int q = 9; q >= 0; --q) i = sigma_apply(q, r, i);  // G = s0∘s1∘…∘s9
    return i;
}
constexpr unsigned Afun(unsigned p) {
    return ((p >> 3) << 3) | ((p & 3u) << 1) | ((p >> 2) & 1u);
}

struct FoldT { unsigned short e[QDEPTH][128][8]; };   // 20 KB
constexpr FoldT make_fold() {
    FoldT t{};
    for (int l = 0; l < QDEPTH; ++l)
        for (unsigned wl = 0; wl < 128; ++wl)
            for (unsigned j = 0; j < 8; ++j) {
                unsigned s = ((wl >> 6) << 9) | (j << 6) | (wl & 63u);
                t.e[l][wl][j] = (unsigned short)Afun(G_apply(l, s));
            }
    return t;
}
__constant__ FoldT FOLD = make_fold();

template <int N, int I = 0, typename F>
__device__ __forceinline__ void static_for(F&& f) {
    if constexpr (I < N) {
        f(std::integral_constant<int, I>{});
        static_for<N, I + 1>(f);
    }
}

__device__ __forceinline__ float fxor(float a, unsigned s) {
    return __uint_as_float(__float_as_uint(a) ^ s);
}
__device__ __forceinline__ f2 fxor2(f2 a, unsigned s) {
    f2 r; r.x = fxor(a.x, s); r.y = fxor(a.y, s); return r;
}
__device__ __forceinline__ f2 swap2(f2 a) { return __builtin_shufflevector(a, a, 1, 0); }
__device__ __forceinline__ f2 pkfma(f2 a, f2 b, f2 c) {
    return __builtin_elementwise_fma(a, b, c);
}

// ---------------------------------------------------------------------------
// Kernel 1: 100 Rot gates -> packed records (Ar,Ar)(-Ai,Ai)(Br,Br)(-Bi,Bi).
// ---------------------------------------------------------------------------
__global__ void gates_kernel(const float* __restrict__ w, float* __restrict__ g) {
    int i = threadIdx.x;
    if (i >= NGATES) return;
    float phi = tanhf(w[3 * i + 0]);
    float th  = tanhf(w[3 * i + 1]);
    float om  = tanhf(w[3 * i + 2]);
    float c = cosf(0.5f * th), s = sinf(0.5f * th);
    float a = 0.5f * (phi + om), d = 0.5f * (phi - om);
    float Ar =  cosf(a) * c, Ai = -sinf(a) * c;    // g00
    float Br = -cosf(d) * s, Bi = -sinf(d) * s;    // g01
    float* p = g + 8 * i;
    p[0] = Ar;  p[1] = Ar;
    p[2] = -Ai; p[3] = Ai;
    p[4] = Br;  p[5] = Br;
    p[6] = -Bi; p[7] = Bi;
}

// Register gate on reg-bit JB of an 8-register state: 4 static pairs.
template <int JB>
__device__ __forceinline__ void apply_gate_reg(f2 (&s)[8], f2 ArP, f2 AiSW,
                                               f2 BrP, f2 BiSW) {
    static_for<4>([&](auto P) {
        constexpr int p  = P.value;
        constexpr int lo = p & ((1 << JB) - 1);
        constexpr int j  = ((p & ~((1 << JB) - 1)) << 1) | lo;
        constexpr int jp = j | (1 << JB);
        f2 a = s[j], b = s[jp];
        f2 as = swap2(a), bs = swap2(b);
        f2 n0 = a * ArP;
        n0 = pkfma(AiSW, as, n0); n0 = pkfma(BrP, b, n0); n0 = pkfma(BiSW, bs, n0);
        f2 n1 = a * (-BrP);
        n1 = pkfma(BiSW, as, n1); n1 = pkfma(ArP, b, n1); n1 = pkfma(-AiSW, bs, n1);
        s[j] = n0; s[jp] = n1;
    });
}

// Lane gate on bit 5 (xor32) / bit 4 (xor16) via permlane swap (r8-verified).
template <bool IS32>
__device__ __forceinline__ void plane_gate(f2& v, f2& w, f2 ArP, f2 AiSW,
                                           f2 BrP, f2 BiSW) {
    unsigned vx = __float_as_uint(v.x), vy = __float_as_uint(v.y);
    unsigned wx = __float_as_uint(w.x), wy = __float_as_uint(w.y);
    unsigned Xx, Xy, Yx, Yy;
    if constexpr (IS32) {
        auto rx = __builtin_amdgcn_permlane32_swap(vx, wx, false, false);
        auto ry = __builtin_amdgcn_permlane32_swap(vy, wy, false, false);
        Xx = rx[0]; Yx = rx[1]; Xy = ry[0]; Yy = ry[1];
    } else {
        auto rx = __builtin_amdgcn_permlane16_swap(vx, wx, false, false);
        auto ry = __builtin_amdgcn_permlane16_swap(vy, wy, false, false);
        Xx = rx[0]; Yx = rx[1]; Xy = ry[0]; Yy = ry[1];
    }
    f2 X, Y;
    X.x = __uint_as_float(Xx); X.y = __uint_as_float(Xy);
    Y.x = __uint_as_float(Yx); Y.y = __uint_as_float(Yy);
    f2 as = swap2(X), bs = swap2(Y);
    f2 n0 = X * ArP;
    n0 = pkfma(AiSW, as, n0); n0 = pkfma(BrP, Y, n0); n0 = pkfma(BiSW, bs, n0);
    f2 n1 = X * (-BrP);
    n1 = pkfma(BiSW, as, n1); n1 = pkfma(ArP, Y, n1); n1 = pkfma(-AiSW, bs, n1);
    unsigned ax = __float_as_uint(n0.x), ay = __float_as_uint(n0.y);
    unsigned bx = __float_as_uint(n1.x), by = __float_as_uint(n1.y);
    if constexpr (IS32) {
        auto ox = __builtin_amdgcn_permlane32_swap(ax, bx, false, false);
        auto oy = __builtin_amdgcn_permlane32_swap(ay, by, false, false);
        v.x = __uint_as_float(ox[0]); v.y = __uint_as_float(oy[0]);
        w.x = __uint_as_float(ox[1]); w.y = __uint_as_float(oy[1]);
    } else {
        auto ox = __builtin_amdgcn_permlane16_swap(ax, bx, false, false);
        auto oy = __builtin_amdgcn_permlane16_swap(ay, by, false, false);
        v.x = __uint_as_float(ox[0]); v.y = __uint_as_float(oy[0]);
        w.x = __uint_as_float(ox[1]); w.y = __uint_as_float(oy[1]);
    }
}

template <int CTRL>
__device__ __forceinline__ f2 dpp2(f2 v) {
    f2 r;
    r.x = __uint_as_float((unsigned)__builtin_amdgcn_mov_dpp(
              (int)__float_as_uint(v.x), CTRL, 0xf, 0xf, true));
    r.y = __uint_as_float((unsigned)__builtin_amdgcn_mov_dpp(
              (int)__float_as_uint(v.y), CTRL, 0xf, 0xf, true));
    return r;
}

// Lane gate via DPP partner + per-lane signs (r8-verified).
template <int CTRL, int M>
__device__ __forceinline__ void dpp_gate(f2 (&s)[8], int lane, f2 ArP, f2 AiSW,
                                         f2 BrP, f2 BiSW) {
    const unsigned sm = (lane & M) ? 0x80000000u : 0u;
    const f2 c2 = fxor2(AiSW, sm);
    const f2 c3 = fxor2(BrP, sm);
    static_for<8>([&](auto J) {
        constexpr int j = J.value;
        f2 a = s[j];
        f2 p = dpp2<CTRL>(a);
        f2 n = a * ArP;
        n = pkfma(c2, swap2(a), n);
        n = pkfma(c3, p, n);
        n = pkfma(BiSW, swap2(p), n);
        s[j] = n;
    });
}

// ---------------------------------------------------------------------------
// Kernel 2: 512 blocks x 256 thr; 2 waves per element; 8 f2 amps per thread.
// One barrier + one LDS round-trip per layer (double-buffered); gates in LDS.
// ---------------------------------------------------------------------------
__global__ __launch_bounds__(256) void sim_kernel(const float* __restrict__ x,
                                                  const float* __restrict__ gtab,
                                                  float* __restrict__ out) {
    __shared__ f2 buf[2][2][NSTATE];     // [parity][elem][A-addr], 32 KB
    __shared__ f2 glds[NGATES * 4];      // packed gate records, 3.2 KB
    __shared__ float wsum[2][2];         // [elem][wave-of-elem]
    const int tid  = threadIdx.x;
    const int e    = tid >> 7;           // element within block
    const int w    = (tid >> 6) & 1;     // wave bit (stored bit 9)
    const int lane = tid & 63;
    const int elem = blockIdx.x * 2 + e;
    const float* xb = x + (size_t)elem * NSTATE;

    // stage gate records once
    for (int i = tid; i < NGATES * 4; i += 256)
        glds[i] = ((const f2*)gtab)[i];

    f2 s[8];

    // ---- amplitude embedding + per-element (cross-wave) L2 normalize ----
    float ss = 0.f;
    static_for<8>([&](auto J) {
        constexpr int j = J.value;
        float v = xb[(w << 9) | (j << 6) | lane];
        s[j].x = v; s[j].y = 0.f;
        ss = fmaf(v, v, ss);
    });
#pragma unroll
    for (int off = 1; off < 64; off <<= 1) ss += __shfl_xor(ss, off);
    if (lane == 0) wsum[e][w] = ss;
    __syncthreads();
    const float nrm = 1.0f / sqrtf(wsum[e][0] + wsum[e][1]);
    static_for<8>([&](auto J) { s[J.value] *= nrm; });

    // LDS write offset within element region: A(s) = (w<<9)|(j<<6)|wb
    const int wb = ((lane >> 3) << 3) | ((lane & 3) << 1) | ((lane >> 2) & 1);

#pragma unroll 1
    for (int l = 0; l < QDEPTH; ++l) {
        const f2* gl = glds + 40 * l;

        // prefetch fold-table entries (16B per thread, coalesced)
        const uint4 fe = *(const uint4*)&FOLD.e[l][tid & 127][0];
        unsigned ew[4] = { fe.x, fe.y, fe.z, fe.w };

        // ---- wires 1,2,3 on reg bits 2,1,0 ----
        apply_gate_reg<2>(s, gl[4],  gl[5],  gl[6],  gl[7]);
        apply_gate_reg<1>(s, gl[8],  gl[9],  gl[10], gl[11]);
        apply_gate_reg<0>(s, gl[12], gl[13], gl[14], gl[15]);

        // ---- wire 4 (bit 5, xor32) / wire 5 (bit 4, xor16) via permlane ----
        {
            f2 a0 = gl[16], a1 = gl[17], a2 = gl[18], a3 = gl[19];
            static_for<4>([&](auto K) {
                constexpr int k = K.value;
                plane_gate<true>(s[2 * k], s[2 * k + 1], a0, a1, a2, a3);
            });
        }
        {
            f2 a0 = gl[20], a1 = gl[21], a2 = gl[22], a3 = gl[23];
            static_for<4>([&](auto K) {
                constexpr int k = K.value;
                plane_gate<false>(s[2 * k], s[2 * k + 1], a0, a1, a2, a3);
            });
        }

        // ---- wire 6 (bit 3, row_ror:8); wires 8,9 (quad_perm) ----
        dpp_gate<0x128, 8>(s, lane, gl[24], gl[25], gl[26], gl[27]);
        dpp_gate<0x04E, 2>(s, lane, gl[32], gl[33], gl[34], gl[35]);
        dpp_gate<0x0B1, 1>(s, lane, gl[36], gl[37], gl[38], gl[39]);

        // ---- write state (A-layout), barrier, fold wires {0,7} = bits {9,2} ----
        f2* B = &buf[l & 1][e][0];
        static_for<8>([&](auto J) {
            constexpr int j = J.value;
            B[(w << 9) | (j << 6) | wb] = s[j];
        });
        __syncthreads();

        const f2 CrP = gl[28], CiSW = gl[29], DrP = gl[30], DiSW = gl[31]; // wire7
        const f2 ErP = gl[0],  EiSW = gl[1],  FrP = gl[2],  FiSW = gl[3];  // wire0
        static_for<8>([&](auto J) {
            constexpr int j = J.value;
            unsigned ks  = (j & 1) ? (ew[j >> 1] >> 16) : (ew[j >> 1] & 0xFFFFu);
            unsigned sm2 = (ks & 1u) << 31;          // h2 row sign
            unsigned sm9 = ((ks >> 9) & 1u) << 31;   // h9 row sign
            f2 vS = B[ks],        vP = B[ks ^ 1u];
            f2 wS = B[ks ^ 512u], wP = B[ks ^ 513u];
            f2 c2 = fxor2(CiSW, sm2), c3 = fxor2(DrP, sm2);
            f2 t1 = vS * CrP;
            t1 = pkfma(c2, swap2(vS), t1);
            t1 = pkfma(c3, vP, t1);
            t1 = pkfma(DiSW, swap2(vP), t1);
            f2 t2 = wS * CrP;
            t2 = pkfma(c2, swap2(wS), t2);
            t2 = pkfma(c3, wP, t2);
            t2 = pkfma(DiSW, swap2(wP), t2);
            f2 e2 = fxor2(EiSW, sm9), e3 = fxor2(FrP, sm9);
            f2 n = t1 * ErP;
            n = pkfma(e2, swap2(t1), n);
            n = pkfma(e3, t2, n);
            n = pkfma(FiSW, swap2(t2), n);
            s[j] = n;
        });
        // no trailing barrier: next layer writes the other parity buffer
    }

    // ---- probs = clip(|amp|^2 * 1024, 0, 1); identity layout ----
    float* ob = out + (size_t)elem * NSTATE;
    static_for<8>([&](auto J) {
        constexpr int j = J.value;
        float p = fmaf(s[j].x, s[j].x, s[j].y * s[j].y) * (float)NSTATE;
        ob[(w << 9) | (j << 6) | lane] = fminf(p, 1.0f);
    });
}

extern "C" void kernel_launch(void* const* d_in, const int* in_sizes, int n_in,
                              void* d_out, int out_size, void* d_ws, size_t ws_size,
                              hipStream_t stream) {
    const float* x = (const float*)d_in[0];   // [1024,1,32,32] f32
    const float* w = (const float*)d_in[1];   // [10,10,3] f32
    float* out   = (float*)d_out;             // [1024,1,32,32] f32
    float* gates = (float*)d_ws;              // 100*8 floats scratch

    gates_kernel<<<1, 128, 0, stream>>>(w, gates);
    sim_kernel<<<512, 256, 0, stream>>>(x, gates, out);
}

// Round 10
// 42.466 us; speedup vs baseline: 1.0445x; 1.0445x over previous
//
#include <hip/hip_runtime.h>
#include <math.h>
#include <type_traits>

#define QDEPTH 10
#define WIRES 10
#define NSTATE 1024
#define NGATES (QDEPTH * WIRES)

typedef float f2 __attribute__((ext_vector_type(2)));
typedef float f4 __attribute__((ext_vector_type(4)));

// ---------------------------------------------------------------------------
// Layout: 1024 blocks x 128 thr (2 waves = 1 element). Stored index
// s = w<<9 | j<<6 | lane (w: wave bit9, j: reg bits 8..6, lane: bits 5..0).
// Wire q <-> bit (9-q):
//   bit 9 (wire 0) + bit 2 (wire 7): folded into per-layer CNOT gather
//   bits 8,7,6 (wires 1-3): register gates (pure pk-FMA)
//   bit 5 (wire 4): permlane32_swap   bit 4 (wire 5): permlane16_swap
//   bit 3 (wire 6): DPP row_ror:8     bits 1,0 (wires 8,9): DPP quad_perm
// LDS address: A(p) = ((p>>3)<<3)|((p&3)<<1)|bit2(p)  ({p,p^4} adjacent),
// then bank-swizzled: A~ = A ^ ((A>>6 & 7)<<1). Fold = two b128 pair-reads
// (at A~(h&~4) and ^512) + coefficient select by h2 + sign trick by h9.
// ---------------------------------------------------------------------------
constexpr unsigned sigma_apply(int q, int r, unsigned i) {
    int cb = 9 - q, tb = 9 - ((q + r) % 10);
    return i ^ (((i >> cb) & 1u) << tb);
}
constexpr unsigned G_apply(int l, unsigned i) {
    int r = (l % 9) + 1;
    for (int q = 9; q >= 0; --q) i = sigma_apply(q, r, i);  // G = s0∘s1∘…∘s9
    return i;
}
constexpr unsigned Afun(unsigned p) {
    return ((p >> 3) << 3) | ((p & 3u) << 1) | ((p >> 2) & 1u);
}
constexpr unsigned Aswz(unsigned p) {
    unsigned a = Afun(p);
    return a ^ (((a >> 6) & 7u) << 1);
}

// entry = (A~(h&~4)>>1) | (bit2(h)<<15); bit9 of the address carries h9.
struct alignas(16) FoldT { unsigned short e[QDEPTH][128][8]; };
constexpr FoldT make_fold() {
    FoldT t{};
    for (int l = 0; l < QDEPTH; ++l)
        for (unsigned wl = 0; wl < 128; ++wl)
            for (unsigned j = 0; j < 8; ++j) {
                unsigned s = ((wl >> 6) << 9) | (j << 6) | (wl & 63u);
                unsigned h = G_apply(l, s);
                unsigned a = Aswz(h & ~4u);           // bit0 == 0
                t.e[l][wl][j] = (unsigned short)((a >> 1) | (((h >> 2) & 1u) << 15));
            }
    return t;
}
__constant__ FoldT FOLD = make_fold();

template <int N, int I = 0, typename F>
__device__ __forceinline__ void static_for(F&& f) {
    if constexpr (I < N) {
        f(std::integral_constant<int, I>{});
        static_for<N, I + 1>(f);
    }
}

__device__ __forceinline__ float fxor(float a, unsigned s) {
    return __uint_as_float(__float_as_uint(a) ^ s);
}
__device__ __forceinline__ f2 fxor2(f2 a, unsigned s) {
    f2 r; r.x = fxor(a.x, s); r.y = fxor(a.y, s); return r;
}
__device__ __forceinline__ f2 swap2(f2 a) { return __builtin_shufflevector(a, a, 1, 0); }
__device__ __forceinline__ f2 pkfma(f2 a, f2 b, f2 c) {
    return __builtin_elementwise_fma(a, b, c);
}

// ---------------------------------------------------------------------------
// Kernel 1: 100 Rot gates -> packed records (Ar,Ar)(-Ai,Ai)(Br,Br)(-Bi,Bi).
// ---------------------------------------------------------------------------
__global__ void gates_kernel(const float* __restrict__ w, float* __restrict__ g) {
    int i = threadIdx.x;
    if (i >= NGATES) return;
    float phi = tanhf(w[3 * i + 0]);
    float th  = tanhf(w[3 * i + 1]);
    float om  = tanhf(w[3 * i + 2]);
    float c = cosf(0.5f * th), s = sinf(0.5f * th);
    float a = 0.5f * (phi + om), d = 0.5f * (phi - om);
    float Ar =  cosf(a) * c, Ai = -sinf(a) * c;    // g00
    float Br = -cosf(d) * s, Bi = -sinf(d) * s;    // g01
    float* p = g + 8 * i;
    p[0] = Ar;  p[1] = Ar;
    p[2] = -Ai; p[3] = Ai;
    p[4] = Br;  p[5] = Br;
    p[6] = -Bi; p[7] = Bi;
}

// Register gate on reg-bit JB of an 8-register state: 4 static pairs.
template <int JB>
__device__ __forceinline__ void apply_gate_reg(f2 (&s)[8], f2 ArP, f2 AiSW,
                                               f2 BrP, f2 BiSW) {
    static_for<4>([&](auto P) {
        constexpr int p  = P.value;
        constexpr int lo = p & ((1 << JB) - 1);
        constexpr int j  = ((p & ~((1 << JB) - 1)) << 1) | lo;
        constexpr int jp = j | (1 << JB);
        f2 a = s[j], b = s[jp];
        f2 as = swap2(a), bs = swap2(b);
        f2 n0 = a * ArP;
        n0 = pkfma(AiSW, as, n0); n0 = pkfma(BrP, b, n0); n0 = pkfma(BiSW, bs, n0);
        f2 n1 = a * (-BrP);
        n1 = pkfma(BiSW, as, n1); n1 = pkfma(ArP, b, n1); n1 = pkfma(-AiSW, bs, n1);
        s[j] = n0; s[jp] = n1;
    });
}

// Lane gate on bit 5 (xor32) / bit 4 (xor16) via permlane swap (r8/r9-verified).
template <bool IS32>
__device__ __forceinline__ void plane_gate(f2& v, f2& w, f2 ArP, f2 AiSW,
                                           f2 BrP, f2 BiSW) {
    unsigned vx = __float_as_uint(v.x), vy = __float_as_uint(v.y);
    unsigned wx = __float_as_uint(w.x), wy = __float_as_uint(w.y);
    unsigned Xx, Xy, Yx, Yy;
    if constexpr (IS32) {
        auto rx = __builtin_amdgcn_permlane32_swap(vx, wx, false, false);
        auto ry = __builtin_amdgcn_permlane32_swap(vy, wy, false, false);
        Xx = rx[0]; Yx = rx[1]; Xy = ry[0]; Yy = ry[1];
    } else {
        auto rx = __builtin_amdgcn_permlane16_swap(vx, wx, false, false);
        auto ry = __builtin_amdgcn_permlane16_swap(vy, wy, false, false);
        Xx = rx[0]; Yx = rx[1]; Xy = ry[0]; Yy = ry[1];
    }
    f2 X, Y;
    X.x = __uint_as_float(Xx); X.y = __uint_as_float(Xy);
    Y.x = __uint_as_float(Yx); Y.y = __uint_as_float(Yy);
    f2 as = swap2(X), bs = swap2(Y);
    f2 n0 = X * ArP;
    n0 = pkfma(AiSW, as, n0); n0 = pkfma(BrP, Y, n0); n0 = pkfma(BiSW, bs, n0);
    f2 n1 = X * (-BrP);
    n1 = pkfma(BiSW, as, n1); n1 = pkfma(ArP, Y, n1); n1 = pkfma(-AiSW, bs, n1);
    unsigned ax = __float_as_uint(n0.x), ay = __float_as_uint(n0.y);
    unsigned bx = __float_as_uint(n1.x), by = __float_as_uint(n1.y);
    if constexpr (IS32) {
        auto ox = __builtin_amdgcn_permlane32_swap(ax, bx, false, false);
        auto oy = __builtin_amdgcn_permlane32_swap(ay, by, false, false);
        v.x = __uint_as_float(ox[0]); v.y = __uint_as_float(oy[0]);
        w.x = __uint_as_float(ox[1]); w.y = __uint_as_float(oy[1]);
    } else {
        auto ox = __builtin_amdgcn_permlane16_swap(ax, bx, false, false);
        auto oy = __builtin_amdgcn_permlane16_swap(ay, by, false, false);
        v.x = __uint_as_float(ox[0]); v.y = __uint_as_float(oy[0]);
        w.x = __uint_as_float(ox[1]); w.y = __uint_as_float(oy[1]);
    }
}

template <int CTRL>
__device__ __forceinline__ f2 dpp2(f2 v) {
    f2 r;
    r.x = __uint_as_float((unsigned)__builtin_amdgcn_mov_dpp(
              (int)__float_as_uint(v.x), CTRL, 0xf, 0xf, true));
    r.y = __uint_as_float((unsigned)__builtin_amdgcn_mov_dpp(
              (int)__float_as_uint(v.y), CTRL, 0xf, 0xf, true));
    return r;
}

// Lane gate via DPP partner + per-lane signs (r8/r9-verified).
template <int CTRL, int M>
__device__ __forceinline__ void dpp_gate(f2 (&s)[8], int lane, f2 ArP, f2 AiSW,
                                         f2 BrP, f2 BiSW) {
    const unsigned sm = (lane & M) ? 0x80000000u : 0u;
    const f2 c2 = fxor2(AiSW, sm);
    const f2 c3 = fxor2(BrP, sm);
    static_for<8>([&](auto J) {
        constexpr int j = J.value;
        f2 a = s[j];
        f2 p = dpp2<CTRL>(a);
        f2 n = a * ArP;
        n = pkfma(c2, swap2(a), n);
        n = pkfma(c3, p, n);
        n = pkfma(BiSW, swap2(p), n);
        s[j] = n;
    });
}

// ---------------------------------------------------------------------------
// Kernel 2: 1024 blocks x 128 thr; 2 waves = 1 element; 8 f2 amps per thread.
// One barrier + one LDS round-trip per layer (dbuf); b128 pair-gathers.
// ---------------------------------------------------------------------------
__global__ __launch_bounds__(128) void sim_kernel(const float* __restrict__ x,
                                                  const float* __restrict__ gtab,
                                                  float* __restrict__ out) {
    __shared__ f2 buf[2][NSTATE];        // [parity][A~-addr], 16 KB
    __shared__ f2 glds[NGATES * 4];      // packed gate records, 3.2 KB
    __shared__ float wsum[2];
    const int tid  = threadIdx.x;
    const int w    = tid >> 6;           // wave bit (stored bit 9)
    const int lane = tid & 63;
    const float* xb = x + (size_t)blockIdx.x * NSTATE;

    // stage gate records once
    for (int i = tid; i < NGATES * 4; i += 128)
        glds[i] = ((const f2*)gtab)[i];

    f2 s[8];

    // ---- amplitude embedding + cross-wave L2 normalize ----
    float ss = 0.f;
    static_for<8>([&](auto J) {
        constexpr int j = J.value;
        float v = xb[(w << 9) | (j << 6) | lane];
        s[j].x = v; s[j].y = 0.f;
        ss = fmaf(v, v, ss);
    });
#pragma unroll
    for (int off = 1; off < 64; off <<= 1) ss += __shfl_xor(ss, off);
    if (lane == 0) wsum[w] = ss;
    __syncthreads();
    const float nrm = 1.0f / sqrtf(wsum[0] + wsum[1]);
    static_for<8>([&](auto J) { s[J.value] *= nrm; });

    // write-address base (6-bit part of A~): A6(lane), j-swizzle applied per j
    const int wb = ((lane >> 3) << 3) | ((lane & 3) << 1) | ((lane >> 2) & 1);

    // prefetch layer-0 fold entries
    uint4 fe = *(const uint4*)&FOLD.e[0][tid][0];

#pragma unroll 1
    for (int l = 0; l < QDEPTH; ++l) {
        const f2* gl = glds + 40 * l;
        unsigned ew[4] = { fe.x, fe.y, fe.z, fe.w };

        // ---- wires 1,2,3 on reg bits 2,1,0 ----
        apply_gate_reg<2>(s, gl[4],  gl[5],  gl[6],  gl[7]);
        apply_gate_reg<1>(s, gl[8],  gl[9],  gl[10], gl[11]);
        apply_gate_reg<0>(s, gl[12], gl[13], gl[14], gl[15]);

        // ---- wire 4 (bit 5, xor32) / wire 5 (bit 4, xor16) via permlane ----
        {
            f2 a0 = gl[16], a1 = gl[17], a2 = gl[18], a3 = gl[19];
            static_for<4>([&](auto K) {
                constexpr int k = K.value;
                plane_gate<true>(s[2 * k], s[2 * k + 1], a0, a1, a2, a3);
            });
        }
        {
            f2 a0 = gl[20], a1 = gl[21], a2 = gl[22], a3 = gl[23];
            static_for<4>([&](auto K) {
                constexpr int k = K.value;
                plane_gate<false>(s[2 * k], s[2 * k + 1], a0, a1, a2, a3);
            });
        }

        // ---- wire 6 (bit 3, row_ror:8); wires 8,9 (quad_perm) ----
        dpp_gate<0x128, 8>(s, lane, gl[24], gl[25], gl[26], gl[27]);
        dpp_gate<0x04E, 2>(s, lane, gl[32], gl[33], gl[34], gl[35]);
        dpp_gate<0x0B1, 1>(s, lane, gl[36], gl[37], gl[38], gl[39]);

        // prefetch next layer's fold entries (hidden under write+barrier+fold)
        if (l < QDEPTH - 1)
            fe = *(const uint4*)&FOLD.e[l + 1][tid][0];

        // ---- write state to A~-layout (per-instruction bijection: free) ----
        f2* B = &buf[l & 1][0];
        static_for<8>([&](auto J) {
            constexpr int j = J.value;
            B[(w << 9) | (j << 6) | (wb ^ (j << 1))] = s[j];
        });
        __syncthreads();

        // ---- fold wires {7,0} = bits {2,9}: two b128 pair reads per amp ----
        const f2 CrP = gl[28], CiSW = gl[29], DrP = gl[30], DiSW = gl[31];
        const f2 ErP = gl[0],  EiSW = gl[1],  FrP = gl[2],  FiSW = gl[3];
        const f2 nDrP = -DrP, nCiSW = -CiSW;
        static_for<8>([&](auto J) {
            constexpr int j = J.value;
            unsigned e16 = (j & 1) ? (ew[j >> 1] >> 16) : (ew[j >> 1] & 0xFFFFu);
            unsigned a0  = (e16 & 0x1FFu) << 1;          // A~(h&~4), carries h9
            bool h2      = (e16 & 0x8000u) != 0;
            unsigned s9  = ((a0 >> 9) & 1u) << 31;
            const f4 pv = *(const f4*)&B[a0];            // self-h9 pair (b2=0,1)
            const f4 qv = *(const f4*)&B[a0 ^ 512u];     // other-h9 pair
            f2 lo1; lo1.x = pv.x; lo1.y = pv.y;
            f2 hi1; hi1.x = pv.z; hi1.y = pv.w;
            f2 lo2; lo2.x = qv.x; lo2.y = qv.y;
            f2 hi2; hi2.x = qv.z; hi2.y = qv.w;
            // wire7 row-h2 coefficients (select, shared by both pairs)
            f2 P = h2 ? nDrP  : CrP;
            f2 Q = h2 ? DiSW  : CiSW;
            f2 R = h2 ? CrP   : DrP;
            f2 S = h2 ? nCiSW : DiSW;
            f2 t1 = lo1 * P;
            t1 = pkfma(Q, swap2(lo1), t1);
            t1 = pkfma(R, hi1, t1);
            t1 = pkfma(S, swap2(hi1), t1);
            f2 t2 = lo2 * P;
            t2 = pkfma(Q, swap2(lo2), t2);
            t2 = pkfma(R, hi2, t2);
            t2 = pkfma(S, swap2(hi2), t2);
            // wire0 row-h9 via sign trick (t1 = self group)
            f2 e2 = fxor2(EiSW, s9), e3 = fxor2(FrP, s9);
            f2 n = t1 * ErP;
            n = pkfma(e2, swap2(t1), n);
            n = pkfma(e3, t2, n);
            n = pkfma(FiSW, swap2(t2), n);
            s[j] = n;
        });
        // no trailing barrier: next layer writes the other parity buffer
    }

    // ---- probs = clip(|amp|^2 * 1024, 0, 1); identity layout ----
    float* ob = out + (size_t)blockIdx.x * NSTATE;
    static_for<8>([&](auto J) {
        constexpr int j = J.value;
        float p = fmaf(s[j].x, s[j].x, s[j].y * s[j].y) * (float)NSTATE;
        ob[(w << 9) | (j << 6) | lane] = fminf(p, 1.0f);
    });
}

extern "C" void kernel_launch(void* const* d_in, const int* in_sizes, int n_in,
                              void* d_out, int out_size, void* d_ws, size_t ws_size,
                              hipStream_t stream) {
    const float* x = (const float*)d_in[0];   // [1024,1,32,32] f32
    const float* w = (const float*)d_in[1];   // [10,10,3] f32
    float* out   = (float*)d_out;             // [1024,1,32,32] f32
    float* gates = (float*)d_ws;              // 100*8 floats scratch

    gates_kernel<<<1, 128, 0, stream>>>(w, gates);
    sim_kernel<<<1024, 128, 0, stream>>>(x, gates, out);
}

// Round 11
// 41.849 us; speedup vs baseline: 1.0599x; 1.0147x over previous
//
#include <hip/hip_runtime.h>
#include <math.h>
#include <type_traits>

#define QDEPTH 10
#define WIRES 10
#define NSTATE 1024
#define NGATES (QDEPTH * WIRES)

typedef float f2 __attribute__((ext_vector_type(2)));
typedef float f4 __attribute__((ext_vector_type(4)));

// ---------------------------------------------------------------------------
// Layout (r8 structure): 1 wave = 1 batch element. Stored index s = j<<6|lane
// (j: 4 reg bits 9..6, lane: 6 bits 5..0). Wire q <-> stored bit (9-q):
//   bits 9..6 (wires 0-3): register gates (pure pk-FMA)
//   bit 5 (wire 4): permlane32_swap   bit 4 (wire 5): permlane16_swap
//   bit 3 (wire 6): DPP row_ror:8    bits 1,0 (wires 8,9): DPP quad_perm
//   bit 2 (wire 7): folded into the per-layer CNOT gather (one b128 read)
// LDS address: A(p) = ((p>>3)<<3)|((p&3)<<1)|bit2(p)  ({p,p^4} adjacent),
// bank-swizzled A~ = A ^ (((A>>6)&7)<<1)  (write side stays a per-instruction
// lane bijection = conflict-free; gather side gains reg-bit bank entropy).
// Zero per-layer barriers (wave-private LDS region); one staging barrier.
// ---------------------------------------------------------------------------
constexpr unsigned sigma_apply(int q, int r, unsigned i) {
    int cb = 9 - q, tb = 9 - ((q + r) % 10);
    return i ^ (((i >> cb) & 1u) << tb);
}
constexpr unsigned G_apply(int l, unsigned i) {
    int r = (l % 9) + 1;
    for (int q = 9; q >= 0; --q) i = sigma_apply(q, r, i);  // G = s0∘s1∘…∘s9
    return i;
}
constexpr unsigned Afun(unsigned p) {
    return ((p >> 3) << 3) | ((p & 3u) << 1) | ((p >> 2) & 1u);
}
constexpr unsigned Aswz(unsigned p) {
    unsigned a = Afun(p);
    return a ^ (((a >> 6) & 7u) << 1);
}

// entry = (A~(h&~4)>>1) | (bit2(h)<<15)
struct alignas(16) FoldT { unsigned short e[QDEPTH][64][16]; };   // 20 KB
constexpr FoldT make_fold() {
    FoldT t{};
    for (int l = 0; l < QDEPTH; ++l)
        for (unsigned lane = 0; lane < 64; ++lane)
            for (unsigned j = 0; j < 16; ++j) {
                unsigned s = (j << 6) | lane;
                unsigned h = G_apply(l, s);
                unsigned a = Aswz(h & ~4u);          // bit0 == 0 (swz keeps it)
                t.e[l][lane][j] =
                    (unsigned short)((a >> 1) | (((h >> 2) & 1u) << 15));
            }
    return t;
}
__constant__ FoldT FOLD = make_fold();

template <int N, int I = 0, typename F>
__device__ __forceinline__ void static_for(F&& f) {
    if constexpr (I < N) {
        f(std::integral_constant<int, I>{});
        static_for<N, I + 1>(f);
    }
}

__device__ __forceinline__ float fxor(float a, unsigned s) {
    return __uint_as_float(__float_as_uint(a) ^ s);
}
__device__ __forceinline__ f2 fxor2(f2 a, unsigned s) {
    f2 r; r.x = fxor(a.x, s); r.y = fxor(a.y, s); return r;
}
__device__ __forceinline__ f2 swap2(f2 a) { return __builtin_shufflevector(a, a, 1, 0); }
__device__ __forceinline__ f2 pkfma(f2 a, f2 b, f2 c) {
    return __builtin_elementwise_fma(a, b, c);
}

// ---------------------------------------------------------------------------
// Kernel 1: 100 Rot gates -> packed records (Ar,Ar)(-Ai,Ai)(Br,Br)(-Bi,Bi).
// ---------------------------------------------------------------------------
__global__ void gates_kernel(const float* __restrict__ w, float* __restrict__ g) {
    int i = threadIdx.x;
    if (i >= NGATES) return;
    float phi = tanhf(w[3 * i + 0]);
    float th  = tanhf(w[3 * i + 1]);
    float om  = tanhf(w[3 * i + 2]);
    float c = cosf(0.5f * th), s = sinf(0.5f * th);
    float a = 0.5f * (phi + om), d = 0.5f * (phi - om);
    float Ar =  cosf(a) * c, Ai = -sinf(a) * c;    // g00
    float Br = -cosf(d) * s, Bi = -sinf(d) * s;    // g01
    float* p = g + 8 * i;
    p[0] = Ar;  p[1] = Ar;
    p[2] = -Ai; p[3] = Ai;
    p[4] = Br;  p[5] = Br;
    p[6] = -Bi; p[7] = Bi;
}

// Register gate on reg-bit JB of a 16-register state: 8 static pairs.
template <int JB>
__device__ __forceinline__ void apply_gate_reg(f2 (&s)[16], f2 ArP, f2 AiSW,
                                               f2 BrP, f2 BiSW) {
    static_for<8>([&](auto P) {
        constexpr int p  = P.value;
        constexpr int lo = p & ((1 << JB) - 1);
        constexpr int j  = ((p & ~((1 << JB) - 1)) << 1) | lo;
        constexpr int jp = j | (1 << JB);
        f2 a = s[j], b = s[jp];
        f2 as = swap2(a), bs = swap2(b);
        f2 n0 = a * ArP;
        n0 = pkfma(AiSW, as, n0); n0 = pkfma(BrP, b, n0); n0 = pkfma(BiSW, bs, n0);
        f2 n1 = a * (-BrP);
        n1 = pkfma(BiSW, as, n1); n1 = pkfma(ArP, b, n1); n1 = pkfma(-AiSW, bs, n1);
        s[j] = n0; s[jp] = n1;
    });
}

// Lane gate on bit 5 (xor32) / bit 4 (xor16) via permlane swap (r8-verified).
template <bool IS32>
__device__ __forceinline__ void plane_gate(f2& v, f2& w, f2 ArP, f2 AiSW,
                                           f2 BrP, f2 BiSW) {
    unsigned vx = __float_as_uint(v.x), vy = __float_as_uint(v.y);
    unsigned wx = __float_as_uint(w.x), wy = __float_as_uint(w.y);
    unsigned Xx, Xy, Yx, Yy;
    if constexpr (IS32) {
        auto rx = __builtin_amdgcn_permlane32_swap(vx, wx, false, false);
        auto ry = __builtin_amdgcn_permlane32_swap(vy, wy, false, false);
        Xx = rx[0]; Yx = rx[1]; Xy = ry[0]; Yy = ry[1];
    } else {
        auto rx = __builtin_amdgcn_permlane16_swap(vx, wx, false, false);
        auto ry = __builtin_amdgcn_permlane16_swap(vy, wy, false, false);
        Xx = rx[0]; Yx = rx[1]; Xy = ry[0]; Yy = ry[1];
    }
    f2 X, Y;
    X.x = __uint_as_float(Xx); X.y = __uint_as_float(Xy);
    Y.x = __uint_as_float(Yx); Y.y = __uint_as_float(Yy);
    f2 as = swap2(X), bs = swap2(Y);
    f2 n0 = X * ArP;
    n0 = pkfma(AiSW, as, n0); n0 = pkfma(BrP, Y, n0); n0 = pkfma(BiSW, bs, n0);
    f2 n1 = X * (-BrP);
    n1 = pkfma(BiSW, as, n1); n1 = pkfma(ArP, Y, n1); n1 = pkfma(-AiSW, bs, n1);
    unsigned ax = __float_as_uint(n0.x), ay = __float_as_uint(n0.y);
    unsigned bx = __float_as_uint(n1.x), by = __float_as_uint(n1.y);
    if constexpr (IS32) {
        auto ox = __builtin_amdgcn_permlane32_swap(ax, bx, false, false);
        auto oy = __builtin_amdgcn_permlane32_swap(ay, by, false, false);
        v.x = __uint_as_float(ox[0]); v.y = __uint_as_float(oy[0]);
        w.x = __uint_as_float(ox[1]); w.y = __uint_as_float(oy[1]);
    } else {
        auto ox = __builtin_amdgcn_permlane16_swap(ax, bx, false, false);
        auto oy = __builtin_amdgcn_permlane16_swap(ay, by, false, false);
        v.x = __uint_as_float(ox[0]); v.y = __uint_as_float(oy[0]);
        w.x = __uint_as_float(ox[1]); w.y = __uint_as_float(oy[1]);
    }
}

template <int CTRL>
__device__ __forceinline__ f2 dpp2(f2 v) {
    f2 r;
    r.x = __uint_as_float((unsigned)__builtin_amdgcn_mov_dpp(
              (int)__float_as_uint(v.x), CTRL, 0xf, 0xf, true));
    r.y = __uint_as_float((unsigned)__builtin_amdgcn_mov_dpp(
              (int)__float_as_uint(v.y), CTRL, 0xf, 0xf, true));
    return r;
}

// Lane gate via DPP partner + per-lane signs (r8-verified).
template <int CTRL, int M>
__device__ __forceinline__ void dpp_gate(f2 (&s)[16], int lane, f2 ArP, f2 AiSW,
                                         f2 BrP, f2 BiSW) {
    const unsigned sm = (lane & M) ? 0x80000000u : 0u;
    const f2 c2 = fxor2(AiSW, sm);
    const f2 c3 = fxor2(BrP, sm);
    static_for<16>([&](auto J) {
        constexpr int j = J.value;
        f2 a = s[j];
        f2 p = dpp2<CTRL>(a);
        f2 n = a * ArP;
        n = pkfma(c2, swap2(a), n);
        n = pkfma(c3, p, n);
        n = pkfma(BiSW, swap2(p), n);
        s[j] = n;
    });
}

// ---------------------------------------------------------------------------
// Kernel 2: 256 blocks x 256 thr = 1024 waves; 1 wave = 1 element; 16 f2/thr.
// Zero per-layer barriers; gates staged in LDS once; fold table prefetched.
// ---------------------------------------------------------------------------
__global__ __launch_bounds__(256) void sim_kernel(const float* __restrict__ x,
                                                  const float* __restrict__ gtab,
                                                  float* __restrict__ out) {
    __shared__ f2 amps[4][NSTATE];       // per-wave private regions, 32 KB
    __shared__ f2 glds[NGATES * 4];      // packed gate records, 3.2 KB
    const int tid  = threadIdx.x;
    const int w    = tid >> 6;
    const int lane = tid & 63;
    const int elem = blockIdx.x * 4 + w;
    const float* xb = x + (size_t)elem * NSTATE;
    f2* myb = amps[w];

    // stage gate records once (only block-wide barrier in the kernel)
    for (int i = tid; i < NGATES * 4; i += 256)
        glds[i] = ((const f2*)gtab)[i];

    f2 s[16];

    // ---- amplitude embedding + per-wave L2 normalize ----
    float ss = 0.f;
    static_for<16>([&](auto J) {
        constexpr int j = J.value;
        float v = xb[(j << 6) | lane];
        s[j].x = v; s[j].y = 0.f;
        ss = fmaf(v, v, ss);
    });
#pragma unroll
    for (int off = 1; off < 64; off <<= 1) ss += __shfl_xor(ss, off);
    const float nrm = 1.0f / sqrtf(ss);
    static_for<16>([&](auto J) { s[J.value] *= nrm; });

    __syncthreads();                     // glds ready

    // write-address lane base of A~ (j-part of swizzle applied per j)
    const int wb = ((lane >> 3) << 3) | ((lane & 3) << 1) | ((lane >> 2) & 1);

    // prefetch layer-0 fold entries (32 B, coalesced)
    uint4 fa = *(const uint4*)&FOLD.e[0][lane][0];
    uint4 fb = *(const uint4*)&FOLD.e[0][lane][8];

#pragma unroll 1
    for (int l = 0; l < QDEPTH; ++l) {
        const f2* gl = glds + 40 * l;
        unsigned ew[8] = { fa.x, fa.y, fa.z, fa.w, fb.x, fb.y, fb.z, fb.w };

        // prefetch next layer's fold entries (hidden under gate compute)
        if (l < QDEPTH - 1) {
            fa = *(const uint4*)&FOLD.e[l + 1][lane][0];
            fb = *(const uint4*)&FOLD.e[l + 1][lane][8];
        }

        // ---- wires 0..3 on reg bits 9..6 ----
        apply_gate_reg<3>(s, gl[0],  gl[1],  gl[2],  gl[3]);
        apply_gate_reg<2>(s, gl[4],  gl[5],  gl[6],  gl[7]);
        apply_gate_reg<1>(s, gl[8],  gl[9],  gl[10], gl[11]);
        apply_gate_reg<0>(s, gl[12], gl[13], gl[14], gl[15]);

        // ---- wire 4 (bit 5, xor32) / wire 5 (bit 4, xor16) via permlane ----
        {
            f2 a0 = gl[16], a1 = gl[17], a2 = gl[18], a3 = gl[19];
            static_for<8>([&](auto K) {
                constexpr int k = K.value;
                plane_gate<true>(s[2 * k], s[2 * k + 1], a0, a1, a2, a3);
            });
        }
        {
            f2 a0 = gl[20], a1 = gl[21], a2 = gl[22], a3 = gl[23];
            static_for<8>([&](auto K) {
                constexpr int k = K.value;
                plane_gate<false>(s[2 * k], s[2 * k + 1], a0, a1, a2, a3);
            });
        }

        // ---- wire 6 (bit 3, row_ror:8); wires 8,9 (quad_perm) ----
        dpp_gate<0x128, 8>(s, lane, gl[24], gl[25], gl[26], gl[27]);
        dpp_gate<0x04E, 2>(s, lane, gl[32], gl[33], gl[34], gl[35]);
        dpp_gate<0x0B1, 1>(s, lane, gl[36], gl[37], gl[38], gl[39]);

        // ---- write state to swizzled A~-layout (wave-private, no barrier) ----
        static_for<16>([&](auto J) {
            constexpr int j = J.value;
            myb[(j << 6) | (wb ^ ((j & 7) << 1))] = s[j];
        });

        // ---- wire 7 (bit 2) folded into CNOT gather: one b128 per amp ----
        {
            const f2 ArP = gl[28], AiSW = gl[29], BrP = gl[30], BiSW = gl[31];
            static_for<16>([&](auto J) {
                constexpr int j = J.value;
                unsigned e16 = (j & 1) ? (ew[j >> 1] >> 16) : (ew[j >> 1] & 0xFFFFu);
                unsigned sm  = (e16 & 0x8000u) << 16;       // h2 -> sign bit
                const f4 pv = *(const f4*)&myb[(e16 & 0x1FFu) << 1];
                f2 v0; v0.x = pv.x; v0.y = pv.y;            // bit2 = 0 source
                f2 v1; v1.x = pv.z; v1.y = pv.w;            // bit2 = 1 source
                bool h2 = (e16 & 0x8000u) != 0;
                f2 a  = h2 ? v1 : v0;                       // self
                f2 pp = h2 ? v0 : v1;                       // partner
                f2 c2 = fxor2(AiSW, sm);
                f2 c3 = fxor2(BrP, sm);
                f2 n = a * ArP;
                n = pkfma(c2, swap2(a), n);
                n = pkfma(c3, pp, n);
                n = pkfma(BiSW, swap2(pp), n);
                s[j] = n;
            });
        }
    }

    // ---- probs = clip(|amp|^2 * 1024, 0, 1); identity layout ----
    float* ob = out + (size_t)elem * NSTATE;
    static_for<16>([&](auto J) {
        constexpr int j = J.value;
        float p = fmaf(s[j].x, s[j].x, s[j].y * s[j].y) * (float)NSTATE;
        ob[(j << 6) | lane] = fminf(p, 1.0f);
    });
}

extern "C" void kernel_launch(void* const* d_in, const int* in_sizes, int n_in,
                              void* d_out, int out_size, void* d_ws, size_t ws_size,
                              hipStream_t stream) {
    const float* x = (const float*)d_in[0];   // [1024,1,32,32] f32
    const float* w = (const float*)d_in[1];   // [10,10,3] f32
    float* out   = (float*)d_out;             // [1024,1,32,32] f32
    float* gates = (float*)d_ws;              // 100*8 floats scratch

    gates_kernel<<<1, 128, 0, stream>>>(w, gates);
    sim_kernel<<<256, 256, 0, stream>>>(x, gates, out);
}

// Round 12
// 37.320 us; speedup vs baseline: 1.1885x; 1.1214x over previous
//
#include <hip/hip_runtime.h>
#include <math.h>
#include <type_traits>

#define QDEPTH 10
#define WIRES 10
#define NSTATE 1024
#define NGATES (QDEPTH * WIRES)

typedef float f2 __attribute__((ext_vector_type(2)));
typedef float f4 __attribute__((ext_vector_type(4)));

// ---------------------------------------------------------------------------
// Layout (r8/r11 structure): 1 wave = 1 batch element. Stored index
// s = j<<6|lane (j: 4 reg bits 9..6, lane: 6 bits 5..0). Wire q <-> bit (9-q):
//   bits 9..6 (wires 0-3): register gates (pure pk-FMA)
//   bit 5 (wire 4): permlane32_swap   bit 4 (wire 5): permlane16_swap
//   bit 3 (wire 6): DPP row_ror:8    bits 1,0 (wires 8,9): DPP quad_perm
//   bit 2 (wire 7): folded into the per-layer CNOT gather (one b128 read)
// LDS address: A(p) = ((p>>3)<<3)|((p&3)<<1)|bit2(p)  ({p,p^4} adjacent),
// bank-swizzled A~ = A ^ (((A>>6)&7)<<1). Zero per-layer barriers
// (wave-private LDS region); one staging barrier. Gate records computed
// IN-KERNEL (fused; no separate gates_kernel dispatch).
// ---------------------------------------------------------------------------
constexpr unsigned sigma_apply(int q, int r, unsigned i) {
    int cb = 9 - q, tb = 9 - ((q + r) % 10);
    return i ^ (((i >> cb) & 1u) << tb);
}
constexpr unsigned G_apply(int l, unsigned i) {
    int r = (l % 9) + 1;
    for (int q = 9; q >= 0; --q) i = sigma_apply(q, r, i);  // G = s0∘s1∘…∘s9
    return i;
}
constexpr unsigned Afun(unsigned p) {
    return ((p >> 3) << 3) | ((p & 3u) << 1) | ((p >> 2) & 1u);
}
constexpr unsigned Aswz(unsigned p) {
    unsigned a = Afun(p);
    return a ^ (((a >> 6) & 7u) << 1);
}

// entry = (A~(h&~4)>>1) | (bit2(h)<<15)
struct alignas(16) FoldT { unsigned short e[QDEPTH][64][16]; };   // 20 KB
constexpr FoldT make_fold() {
    FoldT t{};
    for (int l = 0; l < QDEPTH; ++l)
        for (unsigned lane = 0; lane < 64; ++lane)
            for (unsigned j = 0; j < 16; ++j) {
                unsigned s = (j << 6) | lane;
                unsigned h = G_apply(l, s);
                unsigned a = Aswz(h & ~4u);          // bit0 == 0 (swz keeps it)
                t.e[l][lane][j] =
                    (unsigned short)((a >> 1) | (((h >> 2) & 1u) << 15));
            }
    return t;
}
__constant__ FoldT FOLD = make_fold();

template <int N, int I = 0, typename F>
__device__ __forceinline__ void static_for(F&& f) {
    if constexpr (I < N) {
        f(std::integral_constant<int, I>{});
        static_for<N, I + 1>(f);
    }
}

__device__ __forceinline__ float fxor(float a, unsigned s) {
    return __uint_as_float(__float_as_uint(a) ^ s);
}
__device__ __forceinline__ f2 fxor2(f2 a, unsigned s) {
    f2 r; r.x = fxor(a.x, s); r.y = fxor(a.y, s); return r;
}
__device__ __forceinline__ f2 swap2(f2 a) { return __builtin_shufflevector(a, a, 1, 0); }
__device__ __forceinline__ f2 pkfma(f2 a, f2 b, f2 c) {
    return __builtin_elementwise_fma(a, b, c);
}

// Register gate on reg-bit JB of a 16-register state: 8 static pairs.
template <int JB>
__device__ __forceinline__ void apply_gate_reg(f2 (&s)[16], f2 ArP, f2 AiSW,
                                               f2 BrP, f2 BiSW) {
    static_for<8>([&](auto P) {
        constexpr int p  = P.value;
        constexpr int lo = p & ((1 << JB) - 1);
        constexpr int j  = ((p & ~((1 << JB) - 1)) << 1) | lo;
        constexpr int jp = j | (1 << JB);
        f2 a = s[j], b = s[jp];
        f2 as = swap2(a), bs = swap2(b);
        f2 n0 = a * ArP;
        n0 = pkfma(AiSW, as, n0); n0 = pkfma(BrP, b, n0); n0 = pkfma(BiSW, bs, n0);
        f2 n1 = a * (-BrP);
        n1 = pkfma(BiSW, as, n1); n1 = pkfma(ArP, b, n1); n1 = pkfma(-AiSW, bs, n1);
        s[j] = n0; s[jp] = n1;
    });
}

// Lane gate on bit 5 (xor32) / bit 4 (xor16) via permlane swap (r8-verified).
template <bool IS32>
__device__ __forceinline__ void plane_gate(f2& v, f2& w, f2 ArP, f2 AiSW,
                                           f2 BrP, f2 BiSW) {
    unsigned vx = __float_as_uint(v.x), vy = __float_as_uint(v.y);
    unsigned wx = __float_as_uint(w.x), wy = __float_as_uint(w.y);
    unsigned Xx, Xy, Yx, Yy;
    if constexpr (IS32) {
        auto rx = __builtin_amdgcn_permlane32_swap(vx, wx, false, false);
        auto ry = __builtin_amdgcn_permlane32_swap(vy, wy, false, false);
        Xx = rx[0]; Yx = rx[1]; Xy = ry[0]; Yy = ry[1];
    } else {
        auto rx = __builtin_amdgcn_permlane16_swap(vx, wx, false, false);
        auto ry = __builtin_amdgcn_permlane16_swap(vy, wy, false, false);
        Xx = rx[0]; Yx = rx[1]; Xy = ry[0]; Yy = ry[1];
    }
    f2 X, Y;
    X.x = __uint_as_float(Xx); X.y = __uint_as_float(Xy);
    Y.x = __uint_as_float(Yx); Y.y = __uint_as_float(Yy);
    f2 as = swap2(X), bs = swap2(Y);
    f2 n0 = X * ArP;
    n0 = pkfma(AiSW, as, n0); n0 = pkfma(BrP, Y, n0); n0 = pkfma(BiSW, bs, n0);
    f2 n1 = X * (-BrP);
    n1 = pkfma(BiSW, as, n1); n1 = pkfma(ArP, Y, n1); n1 = pkfma(-AiSW, bs, n1);
    unsigned ax = __float_as_uint(n0.x), ay = __float_as_uint(n0.y);
    unsigned bx = __float_as_uint(n1.x), by = __float_as_uint(n1.y);
    if constexpr (IS32) {
        auto ox = __builtin_amdgcn_permlane32_swap(ax, bx, false, false);
        auto oy = __builtin_amdgcn_permlane32_swap(ay, by, false, false);
        v.x = __uint_as_float(ox[0]); v.y = __uint_as_float(oy[0]);
        w.x = __uint_as_float(ox[1]); w.y = __uint_as_float(oy[1]);
    } else {
        auto ox = __builtin_amdgcn_permlane16_swap(ax, bx, false, false);
        auto oy = __builtin_amdgcn_permlane16_swap(ay, by, false, false);
        v.x = __uint_as_float(ox[0]); v.y = __uint_as_float(oy[0]);
        w.x = __uint_as_float(ox[1]); w.y = __uint_as_float(oy[1]);
    }
}

template <int CTRL>
__device__ __forceinline__ f2 dpp2(f2 v) {
    f2 r;
    r.x = __uint_as_float((unsigned)__builtin_amdgcn_mov_dpp(
              (int)__float_as_uint(v.x), CTRL, 0xf, 0xf, true));
    r.y = __uint_as_float((unsigned)__builtin_amdgcn_mov_dpp(
              (int)__float_as_uint(v.y), CTRL, 0xf, 0xf, true));
    return r;
}

// Lane gate via DPP partner + per-lane signs (r8-verified).
template <int CTRL, int M>
__device__ __forceinline__ void dpp_gate(f2 (&s)[16], int lane, f2 ArP, f2 AiSW,
                                         f2 BrP, f2 BiSW) {
    const unsigned sm = (lane & M) ? 0x80000000u : 0u;
    const f2 c2 = fxor2(AiSW, sm);
    const f2 c3 = fxor2(BrP, sm);
    static_for<16>([&](auto J) {
        constexpr int j = J.value;
        f2 a = s[j];
        f2 p = dpp2<CTRL>(a);
        f2 n = a * ArP;
        n = pkfma(c2, swap2(a), n);
        n = pkfma(c3, p, n);
        n = pkfma(BiSW, swap2(p), n);
        s[j] = n;
    });
}

// ---------------------------------------------------------------------------
// Fused kernel: 256 blocks x 256 thr = 1024 waves; 1 wave = 1 element;
// 16 f2 amps/thread. Gate records computed in-prologue (threads 0..99).
// Zero per-layer barriers; one staging barrier total.
// ---------------------------------------------------------------------------
__global__ __launch_bounds__(256) void sim_kernel(const float* __restrict__ x,
                                                  const float* __restrict__ wts,
                                                  float* __restrict__ out) {
    __shared__ f2 amps[4][NSTATE];       // per-wave private regions, 32 KB
    __shared__ f2 glds[NGATES * 4];      // packed gate records, 3.2 KB
    const int tid  = threadIdx.x;
    const int w    = tid >> 6;
    const int lane = tid & 63;
    const int elem = blockIdx.x * 4 + w;
    const float* xb = x + (size_t)elem * NSTATE;
    f2* myb = amps[w];

    f2 s[16];

    // ---- issue amplitude loads first (HBM latency hides under gate math) ----
    float v[16];
    static_for<16>([&](auto J) {
        constexpr int j = J.value;
        v[j] = xb[(j << 6) | lane];
    });

    // ---- fused gate computation: thread i<100 -> gate i records ----
    // Rot(phi,th,om): g00 = e^{-i(phi+om)/2} cos(th/2), g01 = -e^{+i(phi-om)/2} sin(th/2)
    // record: (Ar,Ar)(-Ai,Ai)(Br,Br)(-Bi,Bi)
    if (tid < NGATES) {
        float phi = tanhf(wts[3 * tid + 0]);
        float th  = tanhf(wts[3 * tid + 1]);
        float om  = tanhf(wts[3 * tid + 2]);
        float c = cosf(0.5f * th), sn = sinf(0.5f * th);
        float a = 0.5f * (phi + om), d = 0.5f * (phi - om);
        float Ar =  cosf(a) * c, Ai = -sinf(a) * c;    // g00
        float Br = -cosf(d) * sn, Bi = -sinf(d) * sn;  // g01
        f2 r0; r0.x = Ar;  r0.y = Ar;
        f2 r1; r1.x = -Ai; r1.y = Ai;
        f2 r2; r2.x = Br;  r2.y = Br;
        f2 r3; r3.x = -Bi; r3.y = Bi;
        glds[4 * tid + 0] = r0;
        glds[4 * tid + 1] = r1;
        glds[4 * tid + 2] = r2;
        glds[4 * tid + 3] = r3;
    }

    // ---- per-wave L2 normalize ----
    float ss = 0.f;
    static_for<16>([&](auto J) {
        constexpr int j = J.value;
        s[j].x = v[j]; s[j].y = 0.f;
        ss = fmaf(v[j], v[j], ss);
    });
#pragma unroll
    for (int off = 1; off < 64; off <<= 1) ss += __shfl_xor(ss, off);
    const float nrm = 1.0f / sqrtf(ss);
    static_for<16>([&](auto J) { s[J.value] *= nrm; });

    __syncthreads();                     // glds ready (only barrier)

    // write-address lane base of A~ (j-part of swizzle applied per j)
    const int wb = ((lane >> 3) << 3) | ((lane & 3) << 1) | ((lane >> 2) & 1);

    // prefetch layer-0 fold entries (32 B, coalesced)
    uint4 fa = *(const uint4*)&FOLD.e[0][lane][0];
    uint4 fb = *(const uint4*)&FOLD.e[0][lane][8];

#pragma unroll 1
    for (int l = 0; l < QDEPTH; ++l) {
        const f2* gl = glds + 40 * l;
        unsigned ew[8] = { fa.x, fa.y, fa.z, fa.w, fb.x, fb.y, fb.z, fb.w };

        // prefetch next layer's fold entries (hidden under gate compute)
        if (l < QDEPTH - 1) {
            fa = *(const uint4*)&FOLD.e[l + 1][lane][0];
            fb = *(const uint4*)&FOLD.e[l + 1][lane][8];
        }

        // ---- wires 0..3 on reg bits 9..6 ----
        apply_gate_reg<3>(s, gl[0],  gl[1],  gl[2],  gl[3]);
        apply_gate_reg<2>(s, gl[4],  gl[5],  gl[6],  gl[7]);
        apply_gate_reg<1>(s, gl[8],  gl[9],  gl[10], gl[11]);
        apply_gate_reg<0>(s, gl[12], gl[13], gl[14], gl[15]);

        // ---- wire 4 (bit 5, xor32) / wire 5 (bit 4, xor16) via permlane ----
        {
            f2 a0 = gl[16], a1 = gl[17], a2 = gl[18], a3 = gl[19];
            static_for<8>([&](auto K) {
                constexpr int k = K.value;
                plane_gate<true>(s[2 * k], s[2 * k + 1], a0, a1, a2, a3);
            });
        }
        {
            f2 a0 = gl[20], a1 = gl[21], a2 = gl[22], a3 = gl[23];
            static_for<8>([&](auto K) {
                constexpr int k = K.value;
                plane_gate<false>(s[2 * k], s[2 * k + 1], a0, a1, a2, a3);
            });
        }

        // ---- wire 6 (bit 3, row_ror:8); wires 8,9 (quad_perm) ----
        dpp_gate<0x128, 8>(s, lane, gl[24], gl[25], gl[26], gl[27]);
        dpp_gate<0x04E, 2>(s, lane, gl[32], gl[33], gl[34], gl[35]);
        dpp_gate<0x0B1, 1>(s, lane, gl[36], gl[37], gl[38], gl[39]);

        // ---- write state to swizzled A~-layout (wave-private, no barrier) ----
        static_for<16>([&](auto J) {
            constexpr int j = J.value;
            myb[(j << 6) | (wb ^ ((j & 7) << 1))] = s[j];
        });

        // ---- wire 7 (bit 2) folded into CNOT gather: one b128 per amp ----
        {
            const f2 ArP = gl[28], AiSW = gl[29], BrP = gl[30], BiSW = gl[31];
            static_for<16>([&](auto J) {
                constexpr int j = J.value;
                unsigned e16 = (j & 1) ? (ew[j >> 1] >> 16) : (ew[j >> 1] & 0xFFFFu);
                unsigned sm  = (e16 & 0x8000u) << 16;       // h2 -> sign bit
                const f4 pv = *(const f4*)&myb[(e16 & 0x1FFu) << 1];
                f2 v0; v0.x = pv.x; v0.y = pv.y;            // bit2 = 0 source
                f2 v1; v1.x = pv.z; v1.y = pv.w;            // bit2 = 1 source
                bool h2 = (e16 & 0x8000u) != 0;
                f2 a  = h2 ? v1 : v0;                       // self
                f2 pp = h2 ? v0 : v1;                       // partner
                f2 c2 = fxor2(AiSW, sm);
                f2 c3 = fxor2(BrP, sm);
                f2 n = a * ArP;
                n = pkfma(c2, swap2(a), n);
                n = pkfma(c3, pp, n);
                n = pkfma(BiSW, swap2(pp), n);
                s[j] = n;
            });
        }
    }

    // ---- probs = clip(|amp|^2 * 1024, 0, 1); identity layout ----
    float* ob = out + (size_t)elem * NSTATE;
    static_for<16>([&](auto J) {
        constexpr int j = J.value;
        float p = fmaf(s[j].x, s[j].x, s[j].y * s[j].y) * (float)NSTATE;
        ob[(j << 6) | lane] = fminf(p, 1.0f);
    });
}

extern "C" void kernel_launch(void* const* d_in, const int* in_sizes, int n_in,
                              void* d_out, int out_size, void* d_ws, size_t ws_size,
                              hipStream_t stream) {
    const float* x = (const float*)d_in[0];   // [1024,1,32,32] f32
    const float* w = (const float*)d_in[1];   // [10,10,3] f32
    float* out = (float*)d_out;               // [1024,1,32,32] f32

    sim_kernel<<<256, 256, 0, stream>>>(x, w, out);
}

// Round 13
// 33.934 us; speedup vs baseline: 1.3071x; 1.0998x over previous
//
#include <hip/hip_runtime.h>
#include <math.h>
#include <type_traits>

#define QDEPTH 10
#define WIRES 10
#define NSTATE 1024
#define NGATES (QDEPTH * WIRES)

typedef float f2 __attribute__((ext_vector_type(2)));
typedef float f4 __attribute__((ext_vector_type(4)));

// ---------------------------------------------------------------------------
// Layout (r8/r11/r12 structure): 1 wave = 1 batch element. Stored index
// s = j<<6|lane (j: 4 reg bits 9..6, lane: 6 bits 5..0). Wire q <-> bit (9-q):
//   bits 9..6 (wires 0-3): register gates (pure pk-FMA)
//   bit 5 (wire 4): permlane32_swap   bit 4 (wire 5): permlane16_swap
//   bit 3 (wire 6): DPP row_ror:8    bits 1,0 (wires 8,9): DPP quad_perm
//   bit 2 (wire 7): folded into the per-layer CNOT gather (one b128 read)
// LDS address: A(p) = ((p>>3)<<3)|((p&3)<<1)|bit2(p)  ({p,p^4} adjacent),
// bank-swizzled A~ = A ^ (((A>>6)&7)<<1). Zero per-layer barriers
// (wave-private LDS region); one staging barrier. Gate records computed
// in-kernel (fused). NEW r13: all 40 per-layer coefficient f2s batch-loaded
// into registers at layer head (kills 10 serial ds_read waits per layer).
// ---------------------------------------------------------------------------
constexpr unsigned sigma_apply(int q, int r, unsigned i) {
    int cb = 9 - q, tb = 9 - ((q + r) % 10);
    return i ^ (((i >> cb) & 1u) << tb);
}
constexpr unsigned G_apply(int l, unsigned i) {
    int r = (l % 9) + 1;
    for (int q = 9; q >= 0; --q) i = sigma_apply(q, r, i);  // G = s0∘s1∘…∘s9
    return i;
}
constexpr unsigned Afun(unsigned p) {
    return ((p >> 3) << 3) | ((p & 3u) << 1) | ((p >> 2) & 1u);
}
constexpr unsigned Aswz(unsigned p) {
    unsigned a = Afun(p);
    return a ^ (((a >> 6) & 7u) << 1);
}

// entry = (A~(h&~4)>>1) | (bit2(h)<<15)
struct alignas(16) FoldT { unsigned short e[QDEPTH][64][16]; };   // 20 KB
constexpr FoldT make_fold() {
    FoldT t{};
    for (int l = 0; l < QDEPTH; ++l)
        for (unsigned lane = 0; lane < 64; ++lane)
            for (unsigned j = 0; j < 16; ++j) {
                unsigned s = (j << 6) | lane;
                unsigned h = G_apply(l, s);
                unsigned a = Aswz(h & ~4u);          // bit0 == 0 (swz keeps it)
                t.e[l][lane][j] =
                    (unsigned short)((a >> 1) | (((h >> 2) & 1u) << 15));
            }
    return t;
}
__constant__ FoldT FOLD = make_fold();

template <int N, int I = 0, typename F>
__device__ __forceinline__ void static_for(F&& f) {
    if constexpr (I < N) {
        f(std::integral_constant<int, I>{});
        static_for<N, I + 1>(f);
    }
}

__device__ __forceinline__ float fxor(float a, unsigned s) {
    return __uint_as_float(__float_as_uint(a) ^ s);
}
__device__ __forceinline__ f2 fxor2(f2 a, unsigned s) {
    f2 r; r.x = fxor(a.x, s); r.y = fxor(a.y, s); return r;
}
__device__ __forceinline__ f2 swap2(f2 a) { return __builtin_shufflevector(a, a, 1, 0); }
__device__ __forceinline__ f2 pkfma(f2 a, f2 b, f2 c) {
    return __builtin_elementwise_fma(a, b, c);
}

// Register gate on reg-bit JB of a 16-register state: 8 static pairs.
template <int JB>
__device__ __forceinline__ void apply_gate_reg(f2 (&s)[16], f2 ArP, f2 AiSW,
                                               f2 BrP, f2 BiSW) {
    static_for<8>([&](auto P) {
        constexpr int p  = P.value;
        constexpr int lo = p & ((1 << JB) - 1);
        constexpr int j  = ((p & ~((1 << JB) - 1)) << 1) | lo;
        constexpr int jp = j | (1 << JB);
        f2 a = s[j], b = s[jp];
        f2 as = swap2(a), bs = swap2(b);
        f2 n0 = a * ArP;
        n0 = pkfma(AiSW, as, n0); n0 = pkfma(BrP, b, n0); n0 = pkfma(BiSW, bs, n0);
        f2 n1 = a * (-BrP);
        n1 = pkfma(BiSW, as, n1); n1 = pkfma(ArP, b, n1); n1 = pkfma(-AiSW, bs, n1);
        s[j] = n0; s[jp] = n1;
    });
}

// Lane gate on bit 5 (xor32) / bit 4 (xor16) via permlane swap (r8-verified).
template <bool IS32>
__device__ __forceinline__ void plane_gate(f2& v, f2& w, f2 ArP, f2 AiSW,
                                           f2 BrP, f2 BiSW) {
    unsigned vx = __float_as_uint(v.x), vy = __float_as_uint(v.y);
    unsigned wx = __float_as_uint(w.x), wy = __float_as_uint(w.y);
    unsigned Xx, Xy, Yx, Yy;
    if constexpr (IS32) {
        auto rx = __builtin_amdgcn_permlane32_swap(vx, wx, false, false);
        auto ry = __builtin_amdgcn_permlane32_swap(vy, wy, false, false);
        Xx = rx[0]; Yx = rx[1]; Xy = ry[0]; Yy = ry[1];
    } else {
        auto rx = __builtin_amdgcn_permlane16_swap(vx, wx, false, false);
        auto ry = __builtin_amdgcn_permlane16_swap(vy, wy, false, false);
        Xx = rx[0]; Yx = rx[1]; Xy = ry[0]; Yy = ry[1];
    }
    f2 X, Y;
    X.x = __uint_as_float(Xx); X.y = __uint_as_float(Xy);
    Y.x = __uint_as_float(Yx); Y.y = __uint_as_float(Yy);
    f2 as = swap2(X), bs = swap2(Y);
    f2 n0 = X * ArP;
    n0 = pkfma(AiSW, as, n0); n0 = pkfma(BrP, Y, n0); n0 = pkfma(BiSW, bs, n0);
    f2 n1 = X * (-BrP);
    n1 = pkfma(BiSW, as, n1); n1 = pkfma(ArP, Y, n1); n1 = pkfma(-AiSW, bs, n1);
    unsigned ax = __float_as_uint(n0.x), ay = __float_as_uint(n0.y);
    unsigned bx = __float_as_uint(n1.x), by = __float_as_uint(n1.y);
    if constexpr (IS32) {
        auto ox = __builtin_amdgcn_permlane32_swap(ax, bx, false, false);
        auto oy = __builtin_amdgcn_permlane32_swap(ay, by, false, false);
        v.x = __uint_as_float(ox[0]); v.y = __uint_as_float(oy[0]);
        w.x = __uint_as_float(ox[1]); w.y = __uint_as_float(oy[1]);
    } else {
        auto ox = __builtin_amdgcn_permlane16_swap(ax, bx, false, false);
        auto oy = __builtin_amdgcn_permlane16_swap(ay, by, false, false);
        v.x = __uint_as_float(ox[0]); v.y = __uint_as_float(oy[0]);
        w.x = __uint_as_float(ox[1]); w.y = __uint_as_float(oy[1]);
    }
}

template <int CTRL>
__device__ __forceinline__ f2 dpp2(f2 v) {
    f2 r;
    r.x = __uint_as_float((unsigned)__builtin_amdgcn_mov_dpp(
              (int)__float_as_uint(v.x), CTRL, 0xf, 0xf, true));
    r.y = __uint_as_float((unsigned)__builtin_amdgcn_mov_dpp(
              (int)__float_as_uint(v.y), CTRL, 0xf, 0xf, true));
    return r;
}

// Lane gate via DPP partner + per-lane signs (r8-verified).
template <int CTRL, int M>
__device__ __forceinline__ void dpp_gate(f2 (&s)[16], int lane, f2 ArP, f2 AiSW,
                                         f2 BrP, f2 BiSW) {
    const unsigned sm = (lane & M) ? 0x80000000u : 0u;
    const f2 c2 = fxor2(AiSW, sm);
    const f2 c3 = fxor2(BrP, sm);
    static_for<16>([&](auto J) {
        constexpr int j = J.value;
        f2 a = s[j];
        f2 p = dpp2<CTRL>(a);
        f2 n = a * ArP;
        n = pkfma(c2, swap2(a), n);
        n = pkfma(c3, p, n);
        n = pkfma(BiSW, swap2(p), n);
        s[j] = n;
    });
}

// ---------------------------------------------------------------------------
// Fused kernel: 256 blocks x 256 thr = 1024 waves; 1 wave = 1 element;
// 16 f2 amps/thread. Gate records computed in-prologue (threads 0..99).
// Zero per-layer barriers; coefficients batch-loaded to regs per layer.
// ---------------------------------------------------------------------------
__global__ __launch_bounds__(256, 1) void sim_kernel(const float* __restrict__ x,
                                                     const float* __restrict__ wts,
                                                     float* __restrict__ out) {
    __shared__ f2 amps[4][NSTATE];       // per-wave private regions, 32 KB
    __shared__ f2 glds[NGATES * 4];      // packed gate records, 3.2 KB
    const int tid  = threadIdx.x;
    const int w    = tid >> 6;
    const int lane = tid & 63;
    const int elem = blockIdx.x * 4 + w;
    const float* xb = x + (size_t)elem * NSTATE;
    f2* myb = amps[w];

    f2 s[16];

    // ---- issue amplitude loads first (HBM latency hides under gate math) ----
    float v[16];
    static_for<16>([&](auto J) {
        constexpr int j = J.value;
        v[j] = xb[(j << 6) | lane];
    });

    // ---- fused gate computation: thread i<100 -> gate i records ----
    if (tid < NGATES) {
        float phi = tanhf(wts[3 * tid + 0]);
        float th  = tanhf(wts[3 * tid + 1]);
        float om  = tanhf(wts[3 * tid + 2]);
        float c = cosf(0.5f * th), sn = sinf(0.5f * th);
        float a = 0.5f * (phi + om), d = 0.5f * (phi - om);
        float Ar =  cosf(a) * c, Ai = -sinf(a) * c;    // g00
        float Br = -cosf(d) * sn, Bi = -sinf(d) * sn;  // g01
        f2 r0; r0.x = Ar;  r0.y = Ar;
        f2 r1; r1.x = -Ai; r1.y = Ai;
        f2 r2; r2.x = Br;  r2.y = Br;
        f2 r3; r3.x = -Bi; r3.y = Bi;
        glds[4 * tid + 0] = r0;
        glds[4 * tid + 1] = r1;
        glds[4 * tid + 2] = r2;
        glds[4 * tid + 3] = r3;
    }

    // ---- per-wave L2 normalize ----
    float ss = 0.f;
    static_for<16>([&](auto J) {
        constexpr int j = J.value;
        s[j].x = v[j]; s[j].y = 0.f;
        ss = fmaf(v[j], v[j], ss);
    });
#pragma unroll
    for (int off = 1; off < 64; off <<= 1) ss += __shfl_xor(ss, off);
    const float nrm = 1.0f / sqrtf(ss);
    static_for<16>([&](auto J) { s[J.value] *= nrm; });

    __syncthreads();                     // glds ready (only barrier)

    // write-address lane base of A~ (j-part of swizzle applied per j)
    const int wb = ((lane >> 3) << 3) | ((lane & 3) << 1) | ((lane >> 2) & 1);

    // prefetch layer-0 fold entries (32 B, coalesced)
    uint4 fa = *(const uint4*)&FOLD.e[0][lane][0];
    uint4 fb = *(const uint4*)&FOLD.e[0][lane][8];

#pragma unroll 1
    for (int l = 0; l < QDEPTH; ++l) {
        const f2* gl = glds + 40 * l;
        unsigned ew[8] = { fa.x, fa.y, fa.z, fa.w, fb.x, fb.y, fb.z, fb.w };

        // ---- batch-load ALL 40 coefficient f2s for this layer into regs ----
        // (issued back-to-back; first stage waits only on its 4, rest stream
        //  in under compute — removes 10 serial dependent LDS waits/layer)
        f2 gr[40];
        static_for<40>([&](auto I_) {
            constexpr int i = I_.value;
            gr[i] = gl[i];
        });

        // prefetch next layer's fold entries (hidden under gate compute)
        if (l < QDEPTH - 1) {
            fa = *(const uint4*)&FOLD.e[l + 1][lane][0];
            fb = *(const uint4*)&FOLD.e[l + 1][lane][8];
        }

        // ---- wires 0..3 on reg bits 9..6 ----
        apply_gate_reg<3>(s, gr[0],  gr[1],  gr[2],  gr[3]);
        apply_gate_reg<2>(s, gr[4],  gr[5],  gr[6],  gr[7]);
        apply_gate_reg<1>(s, gr[8],  gr[9],  gr[10], gr[11]);
        apply_gate_reg<0>(s, gr[12], gr[13], gr[14], gr[15]);

        // ---- wire 4 (bit 5, xor32) / wire 5 (bit 4, xor16) via permlane ----
        static_for<8>([&](auto K) {
            constexpr int k = K.value;
            plane_gate<true>(s[2 * k], s[2 * k + 1], gr[16], gr[17], gr[18], gr[19]);
        });
        static_for<8>([&](auto K) {
            constexpr int k = K.value;
            plane_gate<false>(s[2 * k], s[2 * k + 1], gr[20], gr[21], gr[22], gr[23]);
        });

        // ---- wire 6 (bit 3, row_ror:8); wires 8,9 (quad_perm) ----
        dpp_gate<0x128, 8>(s, lane, gr[24], gr[25], gr[26], gr[27]);
        dpp_gate<0x04E, 2>(s, lane, gr[32], gr[33], gr[34], gr[35]);
        dpp_gate<0x0B1, 1>(s, lane, gr[36], gr[37], gr[38], gr[39]);

        // ---- write state to swizzled A~-layout (wave-private, no barrier) ----
        static_for<16>([&](auto J) {
            constexpr int j = J.value;
            myb[(j << 6) | (wb ^ ((j & 7) << 1))] = s[j];
        });

        // ---- wire 7 (bit 2) folded into CNOT gather: one b128 per amp ----
        {
            const f2 ArP = gr[28], AiSW = gr[29], BrP = gr[30], BiSW = gr[31];
            static_for<16>([&](auto J) {
                constexpr int j = J.value;
                unsigned e16 = (j & 1) ? (ew[j >> 1] >> 16) : (ew[j >> 1] & 0xFFFFu);
                unsigned sm  = (e16 & 0x8000u) << 16;       // h2 -> sign bit
                const f4 pv = *(const f4*)&myb[(e16 & 0x1FFu) << 1];
                f2 v0; v0.x = pv.x; v0.y = pv.y;            // bit2 = 0 source
                f2 v1; v1.x = pv.z; v1.y = pv.w;            // bit2 = 1 source
                bool h2 = (e16 & 0x8000u) != 0;
                f2 a  = h2 ? v1 : v0;                       // self
                f2 pp = h2 ? v0 : v1;                       // partner
                f2 c2 = fxor2(AiSW, sm);
                f2 c3 = fxor2(BrP, sm);
                f2 n = a * ArP;
                n = pkfma(c2, swap2(a), n);
                n = pkfma(c3, pp, n);
                n = pkfma(BiSW, swap2(pp), n);
                s[j] = n;
            });
        }
    }

    // ---- probs = clip(|amp|^2 * 1024, 0, 1); identity layout ----
    float* ob = out + (size_t)elem * NSTATE;
    static_for<16>([&](auto J) {
        constexpr int j = J.value;
        float p = fmaf(s[j].x, s[j].x, s[j].y * s[j].y) * (float)NSTATE;
        ob[(j << 6) | lane] = fminf(p, 1.0f);
    });
}

extern "C" void kernel_launch(void* const* d_in, const int* in_sizes, int n_in,
                              void* d_out, int out_size, void* d_ws, size_t ws_size,
                              hipStream_t stream) {
    const float* x = (const float*)d_in[0];   // [1024,1,32,32] f32
    const float* w = (const float*)d_in[1];   // [10,10,3] f32
    float* out = (float*)d_out;               // [1024,1,32,32] f32

    sim_kernel<<<256, 256, 0, stream>>>(x, w, out);
}